// Round 2
// baseline (509.165 us; speedup 1.0000x reference)
//
#include <hip/hip_runtime.h>

typedef unsigned short u16;
typedef __attribute__((ext_vector_type(4))) float floatx4;
typedef __attribute__((ext_vector_type(8))) short shortx8;

#define B_ 4
#define S_ 2048
#define D_ 1024
#define H_ 16
#define HD_ 64

__device__ __forceinline__ float b2f(u16 u) {
    return __uint_as_float(((unsigned int)u) << 16);
}
__device__ __forceinline__ u16 f2b(float f) {
    unsigned int u = __float_as_uint(f);
    u += 0x7fffu + ((u >> 16) & 1u);
    return (u16)(u >> 16);
}

// ---------------------------------------------------------------------------
// Dtype detector: for bf16 data the LOW u16 of each dword is a real bf16 value
// (exponent in a narrow band); for fp32 data it is random mantissa bits
// (exponent ~uniform). flag=1 -> bf16, flag=0 -> fp32.
// ---------------------------------------------------------------------------
__global__ void detect_dtype(const unsigned int* __restrict__ x, int* __restrict__ flag) {
    const int l = threadIdx.x;  // 64 threads
    int cnt = 0;
    for (int i = l; i < 4096; i += 64) {
        const unsigned int e = (x[i] >> 7) & 0xffu;  // low-half bf16 exponent field
        cnt += (e >= 110u && e <= 134u) ? 1 : 0;
    }
#pragma unroll
    for (int d = 1; d < 64; d <<= 1) cnt += __shfl_xor(cnt, d);
    if (l == 0) *flag = (cnt > 2048) ? 1 : 0;
}

// ---------------------------------------------------------------------------
// Normalize x to bf16 (copy if already bf16, convert if fp32). 8 elems/thread.
// ---------------------------------------------------------------------------
__global__ __launch_bounds__(256) void convert_x(const void* __restrict__ xin,
                                                 u16* __restrict__ xb,
                                                 const int* __restrict__ flag) {
    const int isbf = *flag;
    const size_t i = ((size_t)blockIdx.x * 256 + threadIdx.x) * 8;
    if (isbf) {
        *(uint4*)(xb + i) = *(const uint4*)((const u16*)xin + i);
    } else {
        const float* xf = (const float*)xin;
        float4 a = *(const float4*)(xf + i);
        float4 b = *(const float4*)(xf + i + 4);
        u16 o[8] = {f2b(a.x), f2b(a.y), f2b(a.z), f2b(a.w),
                    f2b(b.x), f2b(b.y), f2b(b.z), f2b(b.w)};
        *(uint4*)(xb + i) = *(uint4*)o;
    }
}

__global__ void convert_bias(const void* __restrict__ bA, const void* __restrict__ bP,
                             u16* __restrict__ bAb, u16* __restrict__ bPb,
                             const int* __restrict__ flag) {
    const int isbf = *flag;
    for (int i = threadIdx.x; i < 3072; i += 256)
        bAb[i] = isbf ? ((const u16*)bA)[i] : f2b(((const float*)bA)[i]);
    for (int i = threadIdx.x; i < 1024; i += 256)
        bPb[i] = isbf ? ((const u16*)bP)[i] : f2b(((const float*)bP)[i]);
}

// ---------------------------------------------------------------------------
// Transpose (+ dtype normalize): in[K][N] (bf16 or fp32) -> out[N][K] bf16.
// ---------------------------------------------------------------------------
__global__ __launch_bounds__(256) void transpose_any(const void* __restrict__ in,
                                                     u16* __restrict__ out,
                                                     int K, int N,
                                                     const int* __restrict__ flag) {
    const int isbf = *flag;
    __shared__ u16 tile[32][33];
    const int tx = threadIdx.x & 31;
    const int ty = threadIdx.x >> 5;
    const int bx = blockIdx.x * 32;  // N index
    const int by = blockIdx.y * 32;  // K index
    if (isbf) {
#pragma unroll
        for (int i = 0; i < 32; i += 8)
            tile[ty + i][tx] = ((const u16*)in)[(size_t)(by + ty + i) * N + bx + tx];
    } else {
#pragma unroll
        for (int i = 0; i < 32; i += 8)
            tile[ty + i][tx] = f2b(((const float*)in)[(size_t)(by + ty + i) * N + bx + tx]);
    }
    __syncthreads();
#pragma unroll
    for (int i = 0; i < 32; i += 8)
        out[(size_t)(bx + ty + i) * K + by + tx] = tile[tx][ty + i];
}

// ---------------------------------------------------------------------------
// C[M x N] = A[M x K] * BT[N x K]^T + bias.  bf16 in, fp32 accum.
// MODE 0: store to out (bf16 or fp32 per flag).
// MODE 1: QKV scatter into q/k/v workspaces laid out [b][h][s][64] (bf16).
// Block: 256 threads (4 waves), tile 128x128, K-step 32.
// ---------------------------------------------------------------------------
template <int MODE>
__global__ __launch_bounds__(256) void gemm_bt(const u16* __restrict__ A,
                                               const u16* __restrict__ BT,
                                               const u16* __restrict__ bias,
                                               void* __restrict__ outv,
                                               int M, int N, int K,
                                               u16* __restrict__ qws,
                                               u16* __restrict__ kws,
                                               u16* __restrict__ vws,
                                               const int* __restrict__ flag) {
    // pitch 40 elems (80 B): frag-read rows stride 20 dwords -> conflict-free
    __shared__ __align__(16) u16 As[128 * 40];
    __shared__ __align__(16) u16 Bs[128 * 40];

    const int isbf = (MODE == 0) ? *flag : 1;
    const int tid = threadIdx.x;
    const int w = tid >> 6, l = tid & 63;
    const int lane_m = l & 15, quad = l >> 4;
    const int bm = blockIdx.x * 128, bn = blockIdx.y * 128;
    const int wm = (w >> 1) * 64, wn = (w & 1) * 64;

    floatx4 acc[4][4];
#pragma unroll
    for (int i = 0; i < 4; i++)
#pragma unroll
        for (int j = 0; j < 4; j++) acc[i][j] = (floatx4){0.f, 0.f, 0.f, 0.f};

    // staging: 512 chunks of 16B per tile; thread handles chunks tid, tid+256
    const int i0 = tid, i1 = tid + 256;
    const int r0 = i0 >> 2, c0 = i0 & 3;
    const int r1 = i1 >> 2, c1 = i1 & 3;

    for (int k0 = 0; k0 < K; k0 += 32) {
        uint4 av0 = *(const uint4*)(A + (size_t)(bm + r0) * K + k0 + c0 * 8);
        uint4 av1 = *(const uint4*)(A + (size_t)(bm + r1) * K + k0 + c1 * 8);
        uint4 bv0 = *(const uint4*)(BT + (size_t)(bn + r0) * K + k0 + c0 * 8);
        uint4 bv1 = *(const uint4*)(BT + (size_t)(bn + r1) * K + k0 + c1 * 8);
        __syncthreads();  // previous iteration's LDS reads complete
        *(uint4*)(As + r0 * 40 + c0 * 8) = av0;
        *(uint4*)(As + r1 * 40 + c1 * 8) = av1;
        *(uint4*)(Bs + r0 * 40 + c0 * 8) = bv0;
        *(uint4*)(Bs + r1 * 40 + c1 * 8) = bv1;
        __syncthreads();

        shortx8 af[4], bf[4];
#pragma unroll
        for (int mb = 0; mb < 4; mb++)
            af[mb] = *(const shortx8*)(As + (wm + mb * 16 + lane_m) * 40 + quad * 8);
#pragma unroll
        for (int nb = 0; nb < 4; nb++)
            bf[nb] = *(const shortx8*)(Bs + (wn + nb * 16 + lane_m) * 40 + quad * 8);
#pragma unroll
        for (int mb = 0; mb < 4; mb++)
#pragma unroll
            for (int nb = 0; nb < 4; nb++)
                acc[mb][nb] = __builtin_amdgcn_mfma_f32_16x16x32_bf16(
                    af[mb], bf[nb], acc[mb][nb], 0, 0, 0);
    }

    // epilogue: C/D layout row=(quad*4+reg)+16*mb(+wm), col=lane_m+16*nb(+wn)
#pragma unroll
    for (int nb = 0; nb < 4; nb++) {
        const int col = bn + wn + nb * 16 + lane_m;
        const float bv = b2f(bias[col]);
#pragma unroll
        for (int mb = 0; mb < 4; mb++) {
            const int rowb = bm + wm + mb * 16 + quad * 4;
#pragma unroll
            for (int r = 0; r < 4; r++) {
                const float v = acc[mb][nb][r] + bv;
                const int rr = rowb + r;
                if (MODE == 0) {
                    if (isbf) ((u16*)outv)[(size_t)rr * N + col] = f2b(v);
                    else ((float*)outv)[(size_t)rr * N + col] = v;
                } else {
                    const int which = col >> 10;  // 0=q,1=k,2=v (uniform per block)
                    const int h = (col >> 6) & 15;
                    const int hd = col & 63;
                    const int b = rr >> 11, s = rr & 2047;
                    u16* dst = which == 0 ? qws : (which == 1 ? kws : vws);
                    dst[((size_t)(b * 16 + h) * 2048 + s) * 64 + hd] = f2b(v);
                }
            }
        }
    }
}

// ---------------------------------------------------------------------------
// Flash attention, causal. Q/K/V in [b*H+h][s][64] bf16.
// Block = 256 threads (4 waves); BQ=128 (32 q-rows/wave); BKV=64.
// Out written to attn_ws[(b*2048+s)*1024 + h*64 + d] (row-major tokens x D).
// ---------------------------------------------------------------------------
__global__ __launch_bounds__(256) void attn_kernel(const u16* __restrict__ Qg,
                                                   const u16* __restrict__ Kg,
                                                   const u16* __restrict__ Vg,
                                                   u16* __restrict__ Og) {
    __shared__ __align__(16) u16 Ks[64 * 72];      // K tile, rows=kv pos
    __shared__ __align__(16) u16 Vt[64 * 72];      // V^T tile, rows=d, cols=kv pos
    __shared__ __align__(16) u16 Ps[4][32 * 72];   // per-wave P tile

    const int tid = threadIdx.x, w = tid >> 6, l = tid & 63;
    const int lane_m = l & 15, quad = l >> 4;
    const int bh = blockIdx.y;
    const int q0 = blockIdx.x * 128;
    const int qw0 = q0 + w * 32;
    const u16* qp = Qg + (size_t)bh * S_ * 64;
    const u16* kp = Kg + (size_t)bh * S_ * 64;
    const u16* vp = Vg + (size_t)bh * S_ * 64;

    // Preload Q fragments: A-layout, rows m=lane_m(+16*mb), k=d=ks*32+quad*8+j
    shortx8 qF[2][2];
#pragma unroll
    for (int mb = 0; mb < 2; mb++)
#pragma unroll
        for (int ks = 0; ks < 2; ks++)
            qF[mb][ks] = *(const shortx8*)(qp + (size_t)(qw0 + mb * 16 + lane_m) * 64 +
                                           ks * 32 + quad * 8);

    floatx4 o_acc[2][4];
#pragma unroll
    for (int mb = 0; mb < 2; mb++)
#pragma unroll
        for (int nbd = 0; nbd < 4; nbd++) o_acc[mb][nbd] = (floatx4){0.f, 0.f, 0.f, 0.f};
    float m_i[2][4], l_i[2][4];
#pragma unroll
    for (int mb = 0; mb < 2; mb++)
#pragma unroll
        for (int r = 0; r < 4; r++) { m_i[mb][r] = -1e30f; l_i[mb][r] = 0.f; }

    const int ntiles = (q0 >> 6) + 2;  // covers kv pos up to q0+127
    const int i0 = tid, i1 = tid + 256;
    u16* psw = &Ps[w][0];

    for (int t = 0; t < ntiles; t++) {
        const int k0 = t * 64;
        // ---- stage K tile (row-major) and V tile (transposed) ----
        uint4 kv0 = *(const uint4*)(kp + (size_t)(k0 + (i0 >> 3)) * 64 + (i0 & 7) * 8);
        uint4 kv1 = *(const uint4*)(kp + (size_t)(k0 + (i1 >> 3)) * 64 + (i1 & 7) * 8);
        const int c2a = i0 >> 6, r2a = i0 & 63;
        const int c2b = i1 >> 6, r2b = i1 & 63;
        uint4 vv0 = *(const uint4*)(vp + (size_t)(k0 + r2a) * 64 + c2a * 8);
        uint4 vv1 = *(const uint4*)(vp + (size_t)(k0 + r2b) * 64 + c2b * 8);
        __syncthreads();  // previous tile's LDS reads complete
        *(uint4*)(Ks + (i0 >> 3) * 72 + (i0 & 7) * 8) = kv0;
        *(uint4*)(Ks + (i1 >> 3) * 72 + (i1 & 7) * 8) = kv1;
        {
            const u16* pv = (const u16*)&vv0;
#pragma unroll
            for (int j = 0; j < 8; j++) Vt[(c2a * 8 + j) * 72 + r2a] = pv[j];
            pv = (const u16*)&vv1;
#pragma unroll
            for (int j = 0; j < 8; j++) Vt[(c2b * 8 + j) * 72 + r2b] = pv[j];
        }
        __syncthreads();

        // ---- S = Q * K^T (M=32, N=64, Kdim=64) ----
        floatx4 sc[2][4];
#pragma unroll
        for (int mb = 0; mb < 2; mb++)
#pragma unroll
            for (int nb = 0; nb < 4; nb++) sc[mb][nb] = (floatx4){0.f, 0.f, 0.f, 0.f};
#pragma unroll
        for (int ks = 0; ks < 2; ks++) {
            shortx8 kF[4];
#pragma unroll
            for (int nb = 0; nb < 4; nb++)
                kF[nb] = *(const shortx8*)(Ks + (nb * 16 + lane_m) * 72 + ks * 32 + quad * 8);
#pragma unroll
            for (int mb = 0; mb < 2; mb++)
#pragma unroll
                for (int nb = 0; nb < 4; nb++)
                    sc[mb][nb] = __builtin_amdgcn_mfma_f32_16x16x32_bf16(
                        qF[mb][ks], kF[nb], sc[mb][nb], 0, 0, 0);
        }

        // ---- scale + causal mask + online softmax (all in registers) ----
#pragma unroll
        for (int mb = 0; mb < 2; mb++) {
#pragma unroll
            for (int r = 0; r < 4; r++) {
                const int qg = qw0 + mb * 16 + quad * 4 + r;
                float sv[4];
                float mloc = -1e30f;
#pragma unroll
                for (int nb = 0; nb < 4; nb++) {
                    const int kg = k0 + nb * 16 + lane_m;
                    const float s = sc[mb][nb][r] * 0.125f;
                    sv[nb] = (kg > qg) ? -1e30f : s;
                    mloc = fmaxf(mloc, sv[nb]);
                }
#pragma unroll
                for (int d = 1; d < 16; d <<= 1) mloc = fmaxf(mloc, __shfl_xor(mloc, d));
                const float mold = m_i[mb][r];
                const float mnew = fmaxf(mold, mloc);
                const float alpha = __expf(mold - mnew);
                float psum = 0.f;
#pragma unroll
                for (int nb = 0; nb < 4; nb++) {
                    const float p = __expf(sv[nb] - mnew);
                    psum += p;
                    psw[(mb * 16 + quad * 4 + r) * 72 + nb * 16 + lane_m] = f2b(p);
                }
#pragma unroll
                for (int d = 1; d < 16; d <<= 1) psum += __shfl_xor(psum, d);
                l_i[mb][r] = l_i[mb][r] * alpha + psum;
                m_i[mb][r] = mnew;
#pragma unroll
                for (int nbd = 0; nbd < 4; nbd++) o_acc[mb][nbd][r] *= alpha;
            }
        }
        __syncthreads();  // P visible (and ordered) before fragment reads

        // ---- O += P * V (M=32, N=64, Kdim=64) ----
#pragma unroll
        for (int ks = 0; ks < 2; ks++) {
            shortx8 pF[2], vF[4];
#pragma unroll
            for (int mb = 0; mb < 2; mb++)
                pF[mb] = *(const shortx8*)(psw + (mb * 16 + lane_m) * 72 + ks * 32 + quad * 8);
#pragma unroll
            for (int nbd = 0; nbd < 4; nbd++)
                vF[nbd] = *(const shortx8*)(Vt + (nbd * 16 + lane_m) * 72 + ks * 32 + quad * 8);
#pragma unroll
            for (int mb = 0; mb < 2; mb++)
#pragma unroll
                for (int nbd = 0; nbd < 4; nbd++)
                    o_acc[mb][nbd] = __builtin_amdgcn_mfma_f32_16x16x32_bf16(
                        pF[mb], vF[nbd], o_acc[mb][nbd], 0, 0, 0);
        }
    }

    // ---- epilogue: O /= l, write [b, s, h*64+d] ----
    const int b = bh >> 4, h = bh & 15;
#pragma unroll
    for (int mb = 0; mb < 2; mb++) {
#pragma unroll
        for (int r = 0; r < 4; r++) {
            const float inv = 1.0f / l_i[mb][r];
            const int qg = qw0 + mb * 16 + quad * 4 + r;
            const size_t base = ((size_t)b * 2048 + qg) * 1024 + h * 64;
#pragma unroll
            for (int nbd = 0; nbd < 4; nbd++)
                Og[base + nbd * 16 + lane_m] = f2b(o_acc[mb][nbd][r] * inv);
        }
    }
}

// ---------------------------------------------------------------------------
extern "C" void kernel_launch(void* const* d_in, const int* in_sizes, int n_in,
                              void* d_out, int out_size, void* d_ws, size_t ws_size,
                              hipStream_t stream) {
    const void* x      = d_in[0];
    // d_in[1] = causal mask — structure is known, ignored
    const void* w_attn = d_in[2];
    const void* b_attn = d_in[3];
    const void* w_proj = d_in[4];
    const void* b_proj = d_in[5];

    // workspace layout (bf16 elements); aws aliases xb (xb dead after QKV gemm)
    u16* qws = (u16*)d_ws;                 // 8388608
    u16* kws = qws + 8388608;
    u16* vws = kws + 8388608;
    u16* xb  = vws + 8388608;              // x normalized to bf16
    u16* aws = xb;                         // attn output (after xb is consumed)
    u16* wtA = xb + 8388608;               // w_attn^T: 3072x1024
    u16* wtP = wtA + 3145728;              // w_proj^T: 1024x1024
    u16* bAb = wtP + 1048576;              // 3072
    u16* bPb = bAb + 3072;                 // 1024
    int* flag = (int*)(bPb + 1024);        // dtype flag (1=bf16, 0=fp32)

    detect_dtype<<<1, 64, 0, stream>>>((const unsigned int*)x, flag);
    convert_x<<<4096, 256, 0, stream>>>(x, xb, flag);
    convert_bias<<<1, 256, 0, stream>>>(b_attn, b_proj, bAb, bPb, flag);
    transpose_any<<<dim3(3072 / 32, 1024 / 32), 256, 0, stream>>>(w_attn, wtA, 1024, 3072, flag);
    transpose_any<<<dim3(1024 / 32, 1024 / 32), 256, 0, stream>>>(w_proj, wtP, 1024, 1024, flag);

    // QKV projection with scatter into [b,h,s,64] per q/k/v
    gemm_bt<1><<<dim3(8192 / 128, 3072 / 128), 256, 0, stream>>>(
        xb, wtA, bAb, nullptr, 8192, 3072, 1024, qws, kws, vws, flag);

    // causal flash attention
    attn_kernel<<<dim3(2048 / 128, B_ * H_), 256, 0, stream>>>(qws, kws, vws, aws);

    // output projection (dtype of d_out selected at runtime via flag)
    gemm_bt<0><<<dim3(8192 / 128, 1024 / 128), 256, 0, stream>>>(
        aws, wtP, bPb, d_out, 8192, 1024, 1024, nullptr, nullptr, nullptr, flag);
}

// Round 3
// 389.962 us; speedup vs baseline: 1.3057x; 1.3057x over previous
//
#include <hip/hip_runtime.h>

typedef unsigned short u16;
typedef __attribute__((ext_vector_type(4))) float floatx4;
typedef __attribute__((ext_vector_type(8))) short shortx8;

#define B_ 4
#define S_ 2048
#define D_ 1024
#define H_ 16
#define HD_ 64

__device__ __forceinline__ float b2f(u16 u) {
    return __uint_as_float(((unsigned int)u) << 16);
}
__device__ __forceinline__ u16 f2b(float f) {
    unsigned int u = __float_as_uint(f);
    u += 0x7fffu + ((u >> 16) & 1u);
    return (u16)(u >> 16);
}
__device__ __forceinline__ unsigned long long pack4(float a, float b, float c, float d) {
    return (unsigned long long)f2b(a) | ((unsigned long long)f2b(b) << 16) |
           ((unsigned long long)f2b(c) << 32) | ((unsigned long long)f2b(d) << 48);
}

// ---------------------------------------------------------------------------
// Dtype detector: bf16 -> flag=1, fp32 -> flag=0 (see round-1 notes).
// ---------------------------------------------------------------------------
__global__ void detect_dtype(const unsigned int* __restrict__ x, int* __restrict__ flag) {
    const int l = threadIdx.x;  // 64 threads
    int cnt = 0;
    for (int i = l; i < 4096; i += 64) {
        const unsigned int e = (x[i] >> 7) & 0xffu;
        cnt += (e >= 110u && e <= 134u) ? 1 : 0;
    }
#pragma unroll
    for (int d = 1; d < 64; d <<= 1) cnt += __shfl_xor(cnt, d);
    if (l == 0) *flag = (cnt > 2048) ? 1 : 0;
}

__global__ __launch_bounds__(256) void convert_x(const void* __restrict__ xin,
                                                 u16* __restrict__ xb,
                                                 const int* __restrict__ flag) {
    const int isbf = *flag;
    const size_t i = ((size_t)blockIdx.x * 256 + threadIdx.x) * 8;
    if (isbf) {
        *(uint4*)(xb + i) = *(const uint4*)((const u16*)xin + i);
    } else {
        const float* xf = (const float*)xin;
        float4 a = *(const float4*)(xf + i);
        float4 b = *(const float4*)(xf + i + 4);
        u16 o[8] = {f2b(a.x), f2b(a.y), f2b(a.z), f2b(a.w),
                    f2b(b.x), f2b(b.y), f2b(b.z), f2b(b.w)};
        *(uint4*)(xb + i) = *(uint4*)o;
    }
}

__global__ void convert_bias(const void* __restrict__ bA, const void* __restrict__ bP,
                             u16* __restrict__ bAb, u16* __restrict__ bPb,
                             const int* __restrict__ flag) {
    const int isbf = *flag;
    for (int i = threadIdx.x; i < 3072; i += 256)
        bAb[i] = isbf ? ((const u16*)bA)[i] : f2b(((const float*)bA)[i]);
    for (int i = threadIdx.x; i < 1024; i += 256)
        bPb[i] = isbf ? ((const u16*)bP)[i] : f2b(((const float*)bP)[i]);
}

// ---------------------------------------------------------------------------
// Transpose (+ dtype normalize): in[K][N] (bf16 or fp32) -> out[N][K] bf16.
// ---------------------------------------------------------------------------
__global__ __launch_bounds__(256) void transpose_any(const void* __restrict__ in,
                                                     u16* __restrict__ out,
                                                     int K, int N,
                                                     const int* __restrict__ flag) {
    const int isbf = *flag;
    __shared__ u16 tile[32][33];
    const int tx = threadIdx.x & 31;
    const int ty = threadIdx.x >> 5;
    const int bx = blockIdx.x * 32;  // N index
    const int by = blockIdx.y * 32;  // K index
    if (isbf) {
#pragma unroll
        for (int i = 0; i < 32; i += 8)
            tile[ty + i][tx] = ((const u16*)in)[(size_t)(by + ty + i) * N + bx + tx];
    } else {
#pragma unroll
        for (int i = 0; i < 32; i += 8)
            tile[ty + i][tx] = f2b(((const float*)in)[(size_t)(by + ty + i) * N + bx + tx]);
    }
    __syncthreads();
#pragma unroll
    for (int i = 0; i < 32; i += 8)
        out[(size_t)(bx + ty + i) * K + by + tx] = tile[tx][ty + i];
}

// ---------------------------------------------------------------------------
// C[M x N] = A[M x K] * BT[N x K]^T + bias.  bf16 in, fp32 accum.
// MODE 0: store to out (bf16 or fp32 per flag).
// MODE 1: QKV scatter into q/k/v ws [b][h][s][64] (bf16); Q pre-scaled by
//         0.125*log2(e) so attention can use exp2 with no per-element scale.
// ---------------------------------------------------------------------------
template <int MODE>
__global__ __launch_bounds__(256) void gemm_bt(const u16* __restrict__ A,
                                               const u16* __restrict__ BT,
                                               const u16* __restrict__ bias,
                                               void* __restrict__ outv,
                                               int M, int N, int K,
                                               u16* __restrict__ qws,
                                               u16* __restrict__ kws,
                                               u16* __restrict__ vws,
                                               const int* __restrict__ flag) {
    __shared__ __align__(16) u16 As[128 * 40];
    __shared__ __align__(16) u16 Bs[128 * 40];

    const int isbf = (MODE == 0) ? *flag : 1;
    const int tid = threadIdx.x;
    const int w = tid >> 6, l = tid & 63;
    const int lane_m = l & 15, quad = l >> 4;
    const int bm = blockIdx.x * 128, bn = blockIdx.y * 128;
    const int wm = (w >> 1) * 64, wn = (w & 1) * 64;

    floatx4 acc[4][4];
#pragma unroll
    for (int i = 0; i < 4; i++)
#pragma unroll
        for (int j = 0; j < 4; j++) acc[i][j] = (floatx4){0.f, 0.f, 0.f, 0.f};

    const int i0 = tid, i1 = tid + 256;
    const int r0 = i0 >> 2, c0 = i0 & 3;
    const int r1 = i1 >> 2, c1 = i1 & 3;

    for (int k0 = 0; k0 < K; k0 += 32) {
        uint4 av0 = *(const uint4*)(A + (size_t)(bm + r0) * K + k0 + c0 * 8);
        uint4 av1 = *(const uint4*)(A + (size_t)(bm + r1) * K + k0 + c1 * 8);
        uint4 bv0 = *(const uint4*)(BT + (size_t)(bn + r0) * K + k0 + c0 * 8);
        uint4 bv1 = *(const uint4*)(BT + (size_t)(bn + r1) * K + k0 + c1 * 8);
        __syncthreads();
        *(uint4*)(As + r0 * 40 + c0 * 8) = av0;
        *(uint4*)(As + r1 * 40 + c1 * 8) = av1;
        *(uint4*)(Bs + r0 * 40 + c0 * 8) = bv0;
        *(uint4*)(Bs + r1 * 40 + c1 * 8) = bv1;
        __syncthreads();

        shortx8 af[4], bf[4];
#pragma unroll
        for (int mb = 0; mb < 4; mb++)
            af[mb] = *(const shortx8*)(As + (wm + mb * 16 + lane_m) * 40 + quad * 8);
#pragma unroll
        for (int nb = 0; nb < 4; nb++)
            bf[nb] = *(const shortx8*)(Bs + (wn + nb * 16 + lane_m) * 40 + quad * 8);
#pragma unroll
        for (int mb = 0; mb < 4; mb++)
#pragma unroll
            for (int nb = 0; nb < 4; nb++)
                acc[mb][nb] = __builtin_amdgcn_mfma_f32_16x16x32_bf16(
                    af[mb], bf[nb], acc[mb][nb], 0, 0, 0);
    }

    const float SCALE_Q = 0.18033688011112042f;  // 0.125 * log2(e)
#pragma unroll
    for (int nb = 0; nb < 4; nb++) {
        const int col = bn + wn + nb * 16 + lane_m;
        const float bv = b2f(bias[col]);
#pragma unroll
        for (int mb = 0; mb < 4; mb++) {
            const int rowb = bm + wm + mb * 16 + quad * 4;
#pragma unroll
            for (int r = 0; r < 4; r++) {
                float v = acc[mb][nb][r] + bv;
                const int rr = rowb + r;
                if (MODE == 0) {
                    if (isbf) ((u16*)outv)[(size_t)rr * N + col] = f2b(v);
                    else ((float*)outv)[(size_t)rr * N + col] = v;
                } else {
                    const int which = col >> 10;  // uniform per block
                    if (which == 0) v *= SCALE_Q;
                    const int h = (col >> 6) & 15;
                    const int hd = col & 63;
                    const int b = rr >> 11, s = rr & 2047;
                    u16* dst = which == 0 ? qws : (which == 1 ? kws : vws);
                    dst[((size_t)(b * 16 + h) * 2048 + s) * 64 + hd] = f2b(v);
                }
            }
        }
    }
}

// ---------------------------------------------------------------------------
// Flash attention, causal, transposed-score scheme.
// S^T = K*Q^T  (col=q, row=kv)  -> softmax is in-register per q-column
// O^T = V^T*P^T (col=q, row=d)  -> alpha/1-over-l already in column pattern
// Block = 256 threads (4 waves); BQ=128 (32 q/wave); BKV=64.
// ---------------------------------------------------------------------------
__global__ __launch_bounds__(256) void attn_kernel(const u16* __restrict__ Qg,
                                                   const u16* __restrict__ Kg,
                                                   const u16* __restrict__ Vg,
                                                   u16* __restrict__ Og) {
    __shared__ __align__(16) u16 Ks[64 * 72];     // K tile  [kv][d]
    __shared__ __align__(16) u16 Vt[64 * 72];     // V^T tile [d][kv]
    __shared__ __align__(16) u16 Ps[4][32 * 72];  // per-wave P^T as [q][kv]

    const int tid = threadIdx.x, w = tid >> 6, l = tid & 63;
    const int lane_m = l & 15, quad = l >> 4;
    const int bh = blockIdx.y;
    // triangular load-balance swizzle: 0,15,1,14,...
    const int xm = (blockIdx.x & 1) ? (15 - (blockIdx.x >> 1)) : (blockIdx.x >> 1);
    const int q0 = xm * 128;
    const int qw0 = q0 + w * 32;
    const u16* qp = Qg + (size_t)bh * S_ * 64;
    const u16* kp = Kg + (size_t)bh * S_ * 64;
    const u16* vp = Vg + (size_t)bh * S_ * 64;

    // Q fragments (B-operand): rows q = qw0 + nb*16 + lane_m, k = ks*32+quad*8
    shortx8 qF[2][2];
#pragma unroll
    for (int nb = 0; nb < 2; nb++)
#pragma unroll
        for (int ks = 0; ks < 2; ks++)
            qF[nb][ks] = *(const shortx8*)(qp + (size_t)(qw0 + nb * 16 + lane_m) * 64 +
                                           ks * 32 + quad * 8);

    floatx4 o_acc[4][2];  // [d-block][q-block]; col=q=lane_m+16nb, row=d
#pragma unroll
    for (int md = 0; md < 4; md++)
#pragma unroll
        for (int nb = 0; nb < 2; nb++) o_acc[md][nb] = (floatx4){0.f, 0.f, 0.f, 0.f};
    float m_i[2] = {-1e30f, -1e30f}, l_i[2] = {0.f, 0.f};

    const int ntiles = (q0 >> 6) + 2;
    const int myend = qw0 + 31;  // wave computes tile iff k0 <= myend
    const int i0 = tid, i1 = tid + 256;
    u16* psw = &Ps[w][0];

    for (int t = 0; t < ntiles; t++) {
        const int k0 = t * 64;
        // ---- cooperative staging: K row-major, V transposed ----
        uint4 kv0 = *(const uint4*)(kp + (size_t)(k0 + (i0 >> 3)) * 64 + (i0 & 7) * 8);
        uint4 kv1 = *(const uint4*)(kp + (size_t)(k0 + (i1 >> 3)) * 64 + (i1 & 7) * 8);
        const int c2a = i0 >> 6, r2a = i0 & 63;
        const int c2b = i1 >> 6, r2b = i1 & 63;
        uint4 vv0 = *(const uint4*)(vp + (size_t)(k0 + r2a) * 64 + c2a * 8);
        uint4 vv1 = *(const uint4*)(vp + (size_t)(k0 + r2b) * 64 + c2b * 8);
        __syncthreads();  // prior tile's LDS reads complete
        *(uint4*)(Ks + (i0 >> 3) * 72 + (i0 & 7) * 8) = kv0;
        *(uint4*)(Ks + (i1 >> 3) * 72 + (i1 & 7) * 8) = kv1;
        {
            const u16* pv = (const u16*)&vv0;
#pragma unroll
            for (int j = 0; j < 8; j++) Vt[(c2a * 8 + j) * 72 + r2a] = pv[j];
            pv = (const u16*)&vv1;
#pragma unroll
            for (int j = 0; j < 8; j++) Vt[(c2b * 8 + j) * 72 + r2b] = pv[j];
        }
        __syncthreads();

        if (k0 <= myend) {  // wave-uniform: skip fully-masked tiles
            // ---- S^T = K * Q^T ----
            floatx4 sc[4][2];
#pragma unroll
            for (int mb = 0; mb < 4; mb++)
#pragma unroll
                for (int nb = 0; nb < 2; nb++) sc[mb][nb] = (floatx4){0.f, 0.f, 0.f, 0.f};
#pragma unroll
            for (int ks = 0; ks < 2; ks++) {
                shortx8 kA[4];
#pragma unroll
                for (int mb = 0; mb < 4; mb++)
                    kA[mb] = *(const shortx8*)(Ks + (mb * 16 + lane_m) * 72 + ks * 32 + quad * 8);
#pragma unroll
                for (int mb = 0; mb < 4; mb++)
#pragma unroll
                    for (int nb = 0; nb < 2; nb++)
                        sc[mb][nb] = __builtin_amdgcn_mfma_f32_16x16x32_bf16(
                            kA[mb], qF[nb][ks], sc[mb][nb], 0, 0, 0);
            }

            const bool maskedTile = (k0 + 63 > qw0);  // one boundary tile per wave
#pragma unroll
            for (int nb = 0; nb < 2; nb++) {
                const int qg = qw0 + nb * 16 + lane_m;
                if (maskedTile) {
#pragma unroll
                    for (int mb = 0; mb < 4; mb++)
#pragma unroll
                        for (int r = 0; r < 4; r++) {
                            const int kvg = k0 + mb * 16 + quad * 4 + r;
                            if (kvg > qg) sc[mb][nb][r] = -1e30f;
                        }
                }
                // in-register max over 16, then cross-quad butterfly (2 shfl)
                float mloc = -1e30f;
#pragma unroll
                for (int mb = 0; mb < 4; mb++) {
                    float a = fmaxf(fmaxf(sc[mb][nb][0], sc[mb][nb][1]),
                                    fmaxf(sc[mb][nb][2], sc[mb][nb][3]));
                    mloc = fmaxf(mloc, a);
                }
                mloc = fmaxf(mloc, __shfl_xor(mloc, 16));
                mloc = fmaxf(mloc, __shfl_xor(mloc, 32));
                const float mnew = fmaxf(m_i[nb], mloc);
                const float alpha = __builtin_amdgcn_exp2f(m_i[nb] - mnew);
                m_i[nb] = mnew;
                float psum = 0.f;
#pragma unroll
                for (int mb = 0; mb < 4; mb++) {
                    const float p0 = __builtin_amdgcn_exp2f(sc[mb][nb][0] - mnew);
                    const float p1 = __builtin_amdgcn_exp2f(sc[mb][nb][1] - mnew);
                    const float p2 = __builtin_amdgcn_exp2f(sc[mb][nb][2] - mnew);
                    const float p3 = __builtin_amdgcn_exp2f(sc[mb][nb][3] - mnew);
                    psum += (p0 + p1) + (p2 + p3);
                    // P^T stored as [q][kv]: 4 consecutive kv -> one b64 write
                    *(unsigned long long*)(psw + (lane_m + 16 * nb) * 72 + mb * 16 + quad * 4) =
                        pack4(p0, p1, p2, p3);
                }
                psum += __shfl_xor(psum, 16);
                psum += __shfl_xor(psum, 32);
                l_i[nb] = l_i[nb] * alpha + psum;
#pragma unroll
                for (int md = 0; md < 4; md++) o_acc[md][nb] *= alpha;
            }
            // no barrier: Ps region is per-wave (compiler inserts lgkmcnt wait)

            // ---- O^T += V^T * P^T ----
#pragma unroll
            for (int ks = 0; ks < 2; ks++) {
                shortx8 vF[4], pF[2];
#pragma unroll
                for (int md = 0; md < 4; md++)
                    vF[md] = *(const shortx8*)(Vt + (md * 16 + lane_m) * 72 + ks * 32 + quad * 8);
#pragma unroll
                for (int nb = 0; nb < 2; nb++)
                    pF[nb] = *(const shortx8*)(psw + (lane_m + 16 * nb) * 72 + ks * 32 + quad * 8);
#pragma unroll
                for (int md = 0; md < 4; md++)
#pragma unroll
                    for (int nb = 0; nb < 2; nb++)
                        o_acc[md][nb] = __builtin_amdgcn_mfma_f32_16x16x32_bf16(
                            vF[md], pF[nb], o_acc[md][nb], 0, 0, 0);
            }
        }
    }

    // ---- epilogue: O^T col=q=lane_m+16nb, row=d=16md+quad*4+r ----
    const int b = bh >> 4, h = bh & 15;
#pragma unroll
    for (int nb = 0; nb < 2; nb++) {
        const float inv = 1.0f / l_i[nb];
        const int qg = qw0 + nb * 16 + lane_m;
        const size_t base = ((size_t)b * 2048 + qg) * 1024 + h * 64;
#pragma unroll
        for (int md = 0; md < 4; md++) {
            *(unsigned long long*)(Og + base + md * 16 + quad * 4) =
                pack4(o_acc[md][nb][0] * inv, o_acc[md][nb][1] * inv,
                      o_acc[md][nb][2] * inv, o_acc[md][nb][3] * inv);
        }
    }
}

// ---------------------------------------------------------------------------
extern "C" void kernel_launch(void* const* d_in, const int* in_sizes, int n_in,
                              void* d_out, int out_size, void* d_ws, size_t ws_size,
                              hipStream_t stream) {
    const void* x      = d_in[0];
    const void* w_attn = d_in[2];
    const void* b_attn = d_in[3];
    const void* w_proj = d_in[4];
    const void* b_proj = d_in[5];

    u16* qws = (u16*)d_ws;                 // 8388608
    u16* kws = qws + 8388608;
    u16* vws = kws + 8388608;
    u16* xb  = vws + 8388608;              // x normalized to bf16
    u16* aws = xb;                         // attn output aliases xb
    u16* wtA = xb + 8388608;               // w_attn^T: 3072x1024
    u16* wtP = wtA + 3145728;              // w_proj^T: 1024x1024
    u16* bAb = wtP + 1048576;              // 3072
    u16* bPb = bAb + 3072;                 // 1024
    int* flag = (int*)(bPb + 1024);

    detect_dtype<<<1, 64, 0, stream>>>((const unsigned int*)x, flag);
    convert_x<<<4096, 256, 0, stream>>>(x, xb, flag);
    convert_bias<<<1, 256, 0, stream>>>(b_attn, b_proj, bAb, bPb, flag);
    transpose_any<<<dim3(3072 / 32, 1024 / 32), 256, 0, stream>>>(w_attn, wtA, 1024, 3072, flag);
    transpose_any<<<dim3(1024 / 32, 1024 / 32), 256, 0, stream>>>(w_proj, wtP, 1024, 1024, flag);

    gemm_bt<1><<<dim3(8192 / 128, 3072 / 128), 256, 0, stream>>>(
        xb, wtA, bAb, nullptr, 8192, 3072, 1024, qws, kws, vws, flag);

    attn_kernel<<<dim3(2048 / 128, B_ * H_), 256, 0, stream>>>(qws, kws, vws, aws);

    gemm_bt<0><<<dim3(8192 / 128, 1024 / 128), 256, 0, stream>>>(
        aws, wtP, bPb, d_out, 8192, 1024, 1024, nullptr, nullptr, nullptr, flag);
}